// Round 7
// baseline (473.649 us; speedup 1.0000x reference)
//
#include <hip/hip_runtime.h>
#include <hip/hip_bf16.h>

#define N 8192
#define FIN 128
#define FOUT 64
#define ALPHA 0.2f
#define LOG2E 1.44269504f
#define KSPLIT 8
#define KSPAN (N / KSPLIT)   // 1024 k per k_pv block
#define UPW 8                // units (32 k each) per wave in k_pv

typedef __attribute__((ext_vector_type(8))) short short8;
typedef __attribute__((ext_vector_type(4))) float f32x4;

static __device__ __forceinline__ unsigned fkey(float x) {
    unsigned u = __float_as_uint(x);
    return (u >> 31) ? ~u : (u | 0x80000000u);
}
static __device__ __forceinline__ float fdecode(unsigned k) {
    unsigned u = (k & 0x80000000u) ? (k & 0x7FFFFFFFu) : ~k;
    return __uint_as_float(u);
}

// ---------------- k_prep: Wh = h@W; s2 = (Wh@a1)*log2e; t2 = (Wh@a2)*log2e --------
__global__ __launch_bounds__(256) void k_prep(const float* __restrict__ h,
                                              const float* __restrict__ W,
                                              const float* __restrict__ a,
                                              float* __restrict__ Wh,
                                              float* __restrict__ s2,
                                              float* __restrict__ t2,
                                              unsigned* __restrict__ keys) {
    __shared__ float lH[16 * FIN];
    __shared__ float lW[FIN * FOUT];
    __shared__ float red[8];
    const int tid = threadIdx.x;
    const int r0 = blockIdx.x * 16;
    {
        const float4* src = (const float4*)(h + (size_t)r0 * FIN);
        float4* dst = (float4*)lH;
        for (int i = tid; i < 16 * FIN / 4; i += 256) dst[i] = src[i];
        const float4* ws_ = (const float4*)W;
        float4* dw = (float4*)lW;
        for (int i = tid; i < FIN * FOUT / 4; i += 256) dw[i] = ws_[i];
    }
    __syncthreads();
    const int wave = tid >> 6, lane = tid & 63;
    float acc[4] = {0.f, 0.f, 0.f, 0.f};
    for (int k = 0; k < FIN; ++k) {
        float wv = lW[k * FOUT + lane];
#pragma unroll
        for (int r = 0; r < 4; ++r)
            acc[r] = fmaf(lH[(wave * 4 + r) * FIN + k], wv, acc[r]);
    }
    const float a1 = a[lane], a2 = a[FOUT + lane];
    float smx = -1e30f, tmx = -1e30f;
#pragma unroll
    for (int r = 0; r < 4; ++r) {
        int row = r0 + wave * 4 + r;
        Wh[(size_t)row * FOUT + lane] = acc[r];
        float sv = acc[r] * a1, tv = acc[r] * a2;
#pragma unroll
        for (int off = 32; off; off >>= 1) {
            sv += __shfl_xor(sv, off);
            tv += __shfl_xor(tv, off);
        }
        sv *= LOG2E; tv *= LOG2E;      // pre-scale: exp(x) -> exp2(x')
        if (lane == 0) { s2[row] = sv; t2[row] = tv; }
        smx = fmaxf(smx, sv);
        tmx = fmaxf(tmx, tv);
    }
    if (lane == 0) { red[wave] = smx; red[4 + wave] = tmx; }
    __syncthreads();
    if (tid == 0) {
        float ms = fmaxf(fmaxf(red[0], red[1]), fmaxf(red[2], red[3]));
        float mt = fmaxf(fmaxf(red[4], red[5]), fmaxf(red[6], red[7]));
        atomicMax(keys + 0, fkey(ms));
        atomicMax(keys + 1, fkey(mt));
    }
}

// ---------------- k_pack: Wh fp32 -> bf16 B-fragment layout ------------------------
// B-frag (16x16x32): lane holds col n = lane&15, k = (lane>>4)*8 + e
__global__ __launch_bounds__(256) void k_pack(const float* __restrict__ Wh,
                                              __hip_bfloat16* __restrict__ WhB) {
    const int c = blockIdx.x;
    const int tn = threadIdx.x >> 6;
    const int lane = threadIdx.x & 63;
    const int quad = lane >> 4, l16 = lane & 15;
    const float* src = Wh + ((size_t)(c * 32 + quad * 8)) * FOUT + tn * 16 + l16;
    union { unsigned short u[8]; short8 v; } frag;
#pragma unroll
    for (int e = 0; e < 8; ++e) {
        __hip_bfloat16 b = __float2bfloat16(src[(size_t)e * FOUT]);
        frag.u[e] = *(unsigned short*)&b;
    }
    *(short8*)&WhB[(((size_t)c * 4 + tn) * 64 + lane) * 8] = frag.v;
}

// ---------------- k_pmat: pure stream — P = bf16(adj * exp2(lrelu(s+t)-m)) --------
// One thread per float4 of adj. Wave = 256 consecutive j of one row (2048 f4/row).
// l_ws[row] accumulates the softmax denominator from the bf16-ROUNDED p values.
__global__ __launch_bounds__(256) void k_pmat(const float* __restrict__ adj,
                                              const float* __restrict__ s2,
                                              const float* __restrict__ t2,
                                              const unsigned* __restrict__ keys,
                                              unsigned long long* __restrict__ P,
                                              float* __restrict__ l_ws) {
    const int tid = blockIdx.x * 256 + threadIdx.x;
    const int row = tid >> 11;
    const int j4 = tid & 2047;
    const int lane = threadIdx.x & 63;
    const float mraw = fdecode(keys[0]) + fdecode(keys[1]);
    const float mm = mraw > 0.f ? mraw : ALPHA * mraw;
    const float sm = s2[row];
    const float4 av = ((const float4*)adj)[tid];
    const float4 tv = ((const float4*)t2)[j4];
    float p[4];
#pragma unroll
    for (int e = 0; e < 4; ++e) {
        float x = sm + ((const float*)&tv)[e];
        float le = fmaxf(x, ALPHA * x);
        p[e] = ((const float*)&av)[e] * exp2f(le - mm);
    }
    union { __hip_bfloat162 h2[2]; unsigned long long u64; } pk;
    pk.h2[0] = __float22bfloat162_rn(make_float2(p[0], p[1]));
    pk.h2[1] = __float22bfloat162_rn(make_float2(p[2], p[3]));
    P[tid] = pk.u64;  // 8 B/thread, coalesced
    float ls = __bfloat162float(pk.h2[0].x) + __bfloat162float(pk.h2[0].y) +
               __bfloat162float(pk.h2[1].x) + __bfloat162float(pk.h2[1].y);
#pragma unroll
    for (int off = 32; off; off >>= 1) ls += __shfl_xor(ls, off);
    if (lane == 0) atomicAdd(&l_ws[row], ls);
}

// ---------------- k_pv: acc[ks] = P[:, ks-span] @ Wh  (no atomics) ----------------
// Grid (N/16, KSPLIT); block 256 = 4 waves owns 16 rows x 1024 k. Wave w: contiguous
// 256-k span = 8 units of 32. A-frag straight from row-major bf16 P (16 B/lane);
// B-frag from L2-resident WhB. Depth-2 register pipeline, fully unrolled.
__global__ __launch_bounds__(256) void k_pv(const __hip_bfloat16* __restrict__ P,
                                            const __hip_bfloat16* __restrict__ WhB,
                                            float* __restrict__ acc_ws) {
    __shared__ float ep[4][4][64][4];  // 16 KB epilogue
    const int wave = threadIdx.x >> 6, lane = threadIdx.x & 63;
    const int quad = lane >> 4, l16 = lane & 15;
    const int i0 = blockIdx.x * 16;
    const int kb = blockIdx.y * KSPAN + wave * 256;   // wave's k base
    const int kc0 = blockIdx.y * (KSPAN / 32) + wave * UPW;
    const short8* PG = (const short8*)(P + (size_t)(i0 + l16) * N + kb + quad * 8);
    const short8* BF = (const short8*)WhB;

    f32x4 acc0 = {0,0,0,0}, acc1 = {0,0,0,0}, acc2 = {0,0,0,0}, acc3 = {0,0,0,0};
    short8 Pp[2], B0[2], B1[2], B2[2], B3[2];
#pragma unroll
    for (int d = 0; d < 2; ++d) {
        Pp[d] = PG[d * 4];                   // unit stride = 32 bf16 = 4 short8
        const size_t c = (size_t)(kc0 + d) * 4;
        B0[d] = BF[(c + 0) * 64 + lane];
        B1[d] = BF[(c + 1) * 64 + lane];
        B2[d] = BF[(c + 2) * 64 + lane];
        B3[d] = BF[(c + 3) * 64 + lane];
    }
#pragma unroll
    for (int u = 0; u < UPW; ++u) {
        const int sl = u & 1;
        acc0 = __builtin_amdgcn_mfma_f32_16x16x32_bf16(Pp[sl], B0[sl], acc0, 0, 0, 0);
        acc1 = __builtin_amdgcn_mfma_f32_16x16x32_bf16(Pp[sl], B1[sl], acc1, 0, 0, 0);
        acc2 = __builtin_amdgcn_mfma_f32_16x16x32_bf16(Pp[sl], B2[sl], acc2, 0, 0, 0);
        acc3 = __builtin_amdgcn_mfma_f32_16x16x32_bf16(Pp[sl], B3[sl], acc3, 0, 0, 0);
        int un = u + 2; if (un > UPW - 1) un = UPW - 1;  // tail clamp (L1-hot reread)
        Pp[sl] = PG[un * 4];
        const size_t c = (size_t)(kc0 + un) * 4;
        B0[sl] = BF[(c + 0) * 64 + lane];
        B1[sl] = BF[(c + 1) * 64 + lane];
        B2[sl] = BF[(c + 2) * 64 + lane];
        B3[sl] = BF[(c + 3) * 64 + lane];
    }

    // cross-wave reduce: 4 waves each hold 4 col-tiles over their k-span
    *(f32x4*)&ep[wave][0][lane][0] = acc0;
    *(f32x4*)&ep[wave][1][lane][0] = acc1;
    *(f32x4*)&ep[wave][2][lane][0] = acc2;
    *(f32x4*)&ep[wave][3][lane][0] = acc3;
    __syncthreads();
    f32x4 tot = {0, 0, 0, 0};
#pragma unroll
    for (int w = 0; w < 4; ++w) {
        f32x4 c = *(const f32x4*)&ep[w][wave][lane][0];
        tot[0] += c[0]; tot[1] += c[1]; tot[2] += c[2]; tot[3] += c[3];
    }
    float* dst = acc_ws + ((size_t)blockIdx.y * N + i0) * FOUT;
#pragma unroll
    for (int r = 0; r < 4; ++r) {
        int row = quad * 4 + r;  // C/D: row=(lane>>4)*4+reg, col=l16 (within tile)
        dst[(size_t)row * FOUT + wave * 16 + l16] = tot[r];  // unique per block: plain store
    }
}

// ---------------- k_final: out = elu( (sum_ks acc[ks]) / l ) -----------------------
__global__ __launch_bounds__(256) void k_final(const float* __restrict__ acc_ws,
                                               const float* __restrict__ l_ws,
                                               float* __restrict__ out) {
    const int idx = blockIdx.x * 256 + threadIdx.x;   // one float4 per thread
    const int row = idx >> 4;                          // 16 float4 per row
    const float inv = 1.0f / l_ws[row];
    float4 sum = {0.f, 0.f, 0.f, 0.f};
#pragma unroll
    for (int ks = 0; ks < KSPLIT; ++ks) {
        float4 a = ((const float4*)(acc_ws + (size_t)ks * N * FOUT))[idx];
        sum.x += a.x; sum.y += a.y; sum.z += a.z; sum.w += a.w;
    }
    float4 o;
#pragma unroll
    for (int r = 0; r < 4; ++r) {
        float v = ((const float*)&sum)[r] * inv;
        ((float*)&o)[r] = v > 0.f ? v : (exp2f(v * LOG2E) - 1.f);
    }
    ((float4*)out)[idx] = o;
}

extern "C" void kernel_launch(void* const* d_in, const int* in_sizes, int n_in,
                              void* d_out, int out_size, void* d_ws, size_t ws_size,
                              hipStream_t stream) {
    const float* h   = (const float*)d_in[0];
    const float* adj = (const float*)d_in[1];
    const float* W   = (const float*)d_in[2];
    const float* a   = (const float*)d_in[3];
    float* out = (float*)d_out;

    // ws layout (bytes): Wh 2M | WhB 1M | s2 32K | t2 32K | l_ws 32K | keys(+pad) 1K
    //                    | P 128M | acc_ws 16M     — total ~147 MB
    char* base = (char*)d_ws;
    float* Wh = (float*)base;                               base += (size_t)N * FOUT * 4;
    __hip_bfloat16* WhB = (__hip_bfloat16*)base;            base += (size_t)N * FOUT * 2;
    float* s2 = (float*)base;                               base += (size_t)N * 4;
    float* t2 = (float*)base;                               base += (size_t)N * 4;
    float* l_ws = (float*)base;                             base += (size_t)N * 4;
    unsigned* keys = (unsigned*)base;                       base += 1024;
    unsigned long long* P = (unsigned long long*)base;      base += (size_t)N * N * 2;
    float* acc_ws = (float*)base;

    hipMemsetAsync(l_ws, 0, (size_t)N * 4 + 1024, stream);  // l_ws + keys
    k_prep<<<N / 16, 256, 0, stream>>>(h, W, a, Wh, s2, t2, keys);
    k_pack<<<N / 32, 256, 0, stream>>>(Wh, WhB);
    k_pmat<<<(size_t)N * N / 4 / 256, 256, 0, stream>>>(adj, s2, t2, keys, P, l_ws);
    dim3 pvg(N / 16, KSPLIT);
    k_pv<<<pvg, 256, 0, stream>>>((const __hip_bfloat16*)P, WhB, acc_ws);
    k_final<<<N * FOUT / 4 / 256, 256, 0, stream>>>(acc_ws, l_ws, out);
}

// Round 8
// 399.089 us; speedup vs baseline: 1.1868x; 1.1868x over previous
//
#include <hip/hip_runtime.h>
#include <hip/hip_bf16.h>

#define N 8192
#define FIN 128
#define FOUT 64
#define ALPHA 0.2f
#define LOG2E 1.44269504f
#define JSPLIT 4
#define JSPAN (N / JSPLIT)    // 2048 j per block
#define STJ 256               // j per stage = 8 units of 32
#define NST (JSPAN / STJ)     // 8 stages

typedef __attribute__((ext_vector_type(8))) short short8;
typedef __attribute__((ext_vector_type(4))) float f32x4;

static __device__ __forceinline__ unsigned fkey(float x) {
    unsigned u = __float_as_uint(x);
    return (u >> 31) ? ~u : (u | 0x80000000u);
}
static __device__ __forceinline__ float fdecode(unsigned k) {
    unsigned u = (k & 0x80000000u) ? (k & 0x7FFFFFFFu) : ~k;
    return __uint_as_float(u);
}
// async global->LDS DMA: per-lane 16B gather; LDS dest = wave-uniform base + lane*16.
static __device__ __forceinline__ void gll16(const float* g, float* l) {
    __builtin_amdgcn_global_load_lds(
        (const __attribute__((address_space(1))) unsigned int*)g,
        (__attribute__((address_space(3))) unsigned int*)l, 16, 0, 0);
}

// ---------------- k_prep: Wh = h@W; s2 = (Wh@a1)*log2e; t2 = (Wh@a2)*log2e --------
__global__ __launch_bounds__(256) void k_prep(const float* __restrict__ h,
                                              const float* __restrict__ W,
                                              const float* __restrict__ a,
                                              float* __restrict__ Wh,
                                              float* __restrict__ s2,
                                              float* __restrict__ t2,
                                              unsigned* __restrict__ keys) {
    __shared__ float lH[16 * FIN];
    __shared__ float lW[FIN * FOUT];
    __shared__ float red[8];
    const int tid = threadIdx.x;
    const int r0 = blockIdx.x * 16;
    {
        const float4* src = (const float4*)(h + (size_t)r0 * FIN);
        float4* dst = (float4*)lH;
        for (int i = tid; i < 16 * FIN / 4; i += 256) dst[i] = src[i];
        const float4* ws_ = (const float4*)W;
        float4* dw = (float4*)lW;
        for (int i = tid; i < FIN * FOUT / 4; i += 256) dw[i] = ws_[i];
    }
    __syncthreads();
    const int wave = tid >> 6, lane = tid & 63;
    float acc[4] = {0.f, 0.f, 0.f, 0.f};
    for (int k = 0; k < FIN; ++k) {
        float wv = lW[k * FOUT + lane];
#pragma unroll
        for (int r = 0; r < 4; ++r)
            acc[r] = fmaf(lH[(wave * 4 + r) * FIN + k], wv, acc[r]);
    }
    const float a1 = a[lane], a2 = a[FOUT + lane];
    float smx = -1e30f, tmx = -1e30f;
#pragma unroll
    for (int r = 0; r < 4; ++r) {
        int row = r0 + wave * 4 + r;
        Wh[(size_t)row * FOUT + lane] = acc[r];
        float sv = acc[r] * a1, tv = acc[r] * a2;
#pragma unroll
        for (int off = 32; off; off >>= 1) {
            sv += __shfl_xor(sv, off);
            tv += __shfl_xor(tv, off);
        }
        sv *= LOG2E; tv *= LOG2E;      // pre-scale: exp(x) -> exp2(x')
        if (lane == 0) { s2[row] = sv; t2[row] = tv; }
        smx = fmaxf(smx, sv);
        tmx = fmaxf(tmx, tv);
    }
    if (lane == 0) { red[wave] = smx; red[4 + wave] = tmx; }
    __syncthreads();
    if (tid == 0) {
        float ms = fmaxf(fmaxf(red[0], red[1]), fmaxf(red[2], red[3]));
        float mt = fmaxf(fmaxf(red[4], red[5]), fmaxf(red[6], red[7]));
        atomicMax(keys + 0, fkey(ms));
        atomicMax(keys + 1, fkey(mt));
    }
}

// ---------------- k_pack: Wh fp32 -> bf16 B-fragment layout ------------------------
// B-frag (16x16x32): lane holds col n = lane&15, k = (lane>>4)*8 + e
__global__ __launch_bounds__(256) void k_pack(const float* __restrict__ Wh,
                                              __hip_bfloat16* __restrict__ WhB) {
    const int c = blockIdx.x;
    const int tn = threadIdx.x >> 6;
    const int lane = threadIdx.x & 63;
    const int quad = lane >> 4, l16 = lane & 15;
    const float* src = Wh + ((size_t)(c * 32 + quad * 8)) * FOUT + tn * 16 + l16;
    union { unsigned short u[8]; short8 v; } frag;
#pragma unroll
    for (int e = 0; e < 8; ++e) {
        __hip_bfloat16 b = __float2bfloat16(src[(size_t)e * FOUT]);
        frag.u[e] = *(unsigned short*)&b;
    }
    *(short8*)&WhB[(((size_t)c * 4 + tn) * 64 + lane) * 8] = frag.v;
}

// ---------------- k_attn: fused mask+softmax+PV ------------------------------------
// Grid (N/16, 4); block 256 thr = 4 waves owns 16 rows x 2048 j.
// Stage = 256 j = 8 units of 32; wave w stages AND computes units {2w, 2w+1}.
// adj DMA'd in A-frag order (16 KB/stage in flight); t2 slice LDS-resident;
// B-frags issued BEFORE the DMA so consuming B never drains the adj prefetch.
__global__ __launch_bounds__(256) void k_attn(const float* __restrict__ adj,
                                              const __hip_bfloat16* __restrict__ WhB,
                                              const float* __restrict__ s2,
                                              const float* __restrict__ t2,
                                              const unsigned* __restrict__ keys,
                                              float* __restrict__ acc_ws,
                                              float* __restrict__ l_ws) {
    __shared__ float bufA[2][8 * 512];   // 2 x 16 KB adj stages; [0] reused in epilogue
    __shared__ float tl[JSPAN];          // 8 KB t slice; reused for shl in epilogue
    const int wave = threadIdx.x >> 6, lane = threadIdx.x & 63;
    const int quad = lane >> 4, l16 = lane & 15;
    const int i0 = blockIdx.x * 16;
    const int jb = blockIdx.y * JSPAN;
    const int u0 = 2 * wave;

    // t2 slice -> LDS (one-time; removes t from the vmcnt stream)
    {
        const float4* src = (const float4*)(t2 + jb);
        float4* dst = (float4*)tl;
        for (int i = threadIdx.x; i < JSPAN / 4; i += 256) dst[i] = src[i];
    }
    // prologue: DMA stage 0 (wave w stages units 2w, 2w+1)
    const float* gaw = adj + (size_t)(i0 + l16) * N + jb + quad * 8;
    gll16(gaw + u0 * 32,      &bufA[0][u0 * 512]);
    gll16(gaw + u0 * 32 + 4,  &bufA[0][u0 * 512 + 256]);
    gll16(gaw + u0 * 32 + 32, &bufA[0][(u0 + 1) * 512]);
    gll16(gaw + u0 * 32 + 36, &bufA[0][(u0 + 1) * 512 + 256]);

    const float mraw = fdecode(keys[0]) + fdecode(keys[1]);
    const float mm = mraw > 0.f ? mraw : ALPHA * mraw;
    const float sm = s2[i0 + l16];
    const short8* BF = (const short8*)WhB;

    f32x4 acc0 = {0,0,0,0}, acc1 = {0,0,0,0}, acc2 = {0,0,0,0}, acc3 = {0,0,0,0};
    float lsum = 0.f;
    __syncthreads();

    for (int st = 0; st < NST; ++st) {
        const int b = st & 1;
        // (1) B-fragments for this stage's two units — issued FIRST so their
        //     waitcnt leaves the (newer) next-stage DMA outstanding.
        const size_t kc = (size_t)(blockIdx.y * (JSPAN / 32) + st * 8 + u0) * 4;
        short8 B00 = BF[(kc + 0) * 64 + lane];
        short8 B01 = BF[(kc + 1) * 64 + lane];
        short8 B02 = BF[(kc + 2) * 64 + lane];
        short8 B03 = BF[(kc + 3) * 64 + lane];
        short8 B10 = BF[(kc + 4) * 64 + lane];
        short8 B11 = BF[(kc + 5) * 64 + lane];
        short8 B12 = BF[(kc + 6) * 64 + lane];
        short8 B13 = BF[(kc + 7) * 64 + lane];
        __builtin_amdgcn_sched_barrier(0);   // pin: B loads before DMA
        // (2) DMA next stage's adj
        if (st + 1 < NST) {
            const float* g = gaw + (st + 1) * STJ + u0 * 32;
            float* d = &bufA[b ^ 1][u0 * 512];
            gll16(g, d);
            gll16(g + 4, d + 256);
            gll16(g + 32, d + 512);
            gll16(g + 36, d + 768);
        }
        __builtin_amdgcn_sched_barrier(0);   // pin: DMA before compute
        // (3) compute units u0, u0+1 from bufA[b]
#pragma unroll
        for (int uu = 0; uu < 2; ++uu) {
            const int ul = u0 + uu;
            const float* Au = &bufA[b][ul * 512];
            float4 alo = *(const float4*)(Au + lane * 4);
            float4 ahi = *(const float4*)(Au + 256 + lane * 4);
            const float* Tp = tl + st * STJ + ul * 32 + quad * 8;
            float4 tlo = *(const float4*)Tp;
            float4 thi = *(const float4*)(Tp + 4);
            union { __hip_bfloat162 h2[4]; short8 v; } af;
#pragma unroll
            for (int pp = 0; pp < 4; ++pp) {
                float a0 = (pp < 2) ? ((const float*)&alo)[2 * pp]     : ((const float*)&ahi)[2 * pp - 4];
                float a1 = (pp < 2) ? ((const float*)&alo)[2 * pp + 1] : ((const float*)&ahi)[2 * pp - 3];
                float t0 = (pp < 2) ? ((const float*)&tlo)[2 * pp]     : ((const float*)&thi)[2 * pp - 4];
                float t1 = (pp < 2) ? ((const float*)&tlo)[2 * pp + 1] : ((const float*)&thi)[2 * pp - 3];
                float x0 = sm + t0,                x1 = sm + t1;
                float le0 = fmaxf(x0, ALPHA * x0), le1 = fmaxf(x1, ALPHA * x1);
                float p0 = a0 * exp2f(le0 - mm),   p1 = a1 * exp2f(le1 - mm);
                __hip_bfloat162 pb = __float22bfloat162_rn(make_float2(p0, p1));
                af.h2[pp] = pb;
                lsum += __bfloat162float(pb.x) + __bfloat162float(pb.y);
            }
            if (uu == 0) {
                acc0 = __builtin_amdgcn_mfma_f32_16x16x32_bf16(af.v, B00, acc0, 0, 0, 0);
                acc1 = __builtin_amdgcn_mfma_f32_16x16x32_bf16(af.v, B01, acc1, 0, 0, 0);
                acc2 = __builtin_amdgcn_mfma_f32_16x16x32_bf16(af.v, B02, acc2, 0, 0, 0);
                acc3 = __builtin_amdgcn_mfma_f32_16x16x32_bf16(af.v, B03, acc3, 0, 0, 0);
            } else {
                acc0 = __builtin_amdgcn_mfma_f32_16x16x32_bf16(af.v, B10, acc0, 0, 0, 0);
                acc1 = __builtin_amdgcn_mfma_f32_16x16x32_bf16(af.v, B11, acc1, 0, 0, 0);
                acc2 = __builtin_amdgcn_mfma_f32_16x16x32_bf16(af.v, B12, acc2, 0, 0, 0);
                acc3 = __builtin_amdgcn_mfma_f32_16x16x32_bf16(af.v, B13, acc3, 0, 0, 0);
            }
        }
        __syncthreads();  // DMA drained + all waves done with buf b
    }

    // lsum: lanes {m, m+16, m+32, m+48} hold row-m partials for this wave's units
    lsum += __shfl_xor(lsum, 16);
    lsum += __shfl_xor(lsum, 32);

    // epilogue: reuse bufA[0] (4096 f) for acc exchange, tl for row sums
    float* accr = &bufA[0][0];
    float* shlp = tl;
    *(f32x4*)&accr[((wave * 4 + 0) * 64 + lane) * 4] = acc0;
    *(f32x4*)&accr[((wave * 4 + 1) * 64 + lane) * 4] = acc1;
    *(f32x4*)&accr[((wave * 4 + 2) * 64 + lane) * 4] = acc2;
    *(f32x4*)&accr[((wave * 4 + 3) * 64 + lane) * 4] = acc3;
    if (lane < 16) shlp[wave * 16 + lane] = lsum;
    __syncthreads();

    const int tile = wave;
    f32x4 tot = {0, 0, 0, 0};
#pragma unroll
    for (int w = 0; w < 4; ++w) {
        f32x4 c = *(const f32x4*)&accr[((w * 4 + tile) * 64 + lane) * 4];
        tot[0] += c[0]; tot[1] += c[1]; tot[2] += c[2]; tot[3] += c[3];
    }
#pragma unroll
    for (int r = 0; r < 4; ++r) {
        int row = quad * 4 + r;  // C/D: row=(lane>>4)*4+reg, col=l16 within tile
        atomicAdd(&acc_ws[(size_t)(i0 + row) * FOUT + tile * 16 + l16], tot[r]);
    }
    if (wave == 0 && lane < 16) {
        float lv = shlp[lane] + shlp[16 + lane] + shlp[32 + lane] + shlp[48 + lane];
        atomicAdd(&l_ws[i0 + lane], lv);
    }
}

// ---------------- k_final: out = elu(acc/l) ---------------------------------------
__global__ __launch_bounds__(256) void k_final(const float* __restrict__ acc_ws,
                                               const float* __restrict__ l_ws,
                                               float* __restrict__ out) {
    const int idx = blockIdx.x * 256 + threadIdx.x;   // one float4 per thread
    const int row = idx >> 4;                          // 16 float4 per row
    const float inv = 1.0f / l_ws[row];
    float4 a = ((const float4*)acc_ws)[idx];
    float4 o;
#pragma unroll
    for (int r = 0; r < 4; ++r) {
        float v = ((const float*)&a)[r] * inv;
        ((float*)&o)[r] = v > 0.f ? v : (exp2f(v * LOG2E) - 1.f);
    }
    ((float4*)out)[idx] = o;
}

extern "C" void kernel_launch(void* const* d_in, const int* in_sizes, int n_in,
                              void* d_out, int out_size, void* d_ws, size_t ws_size,
                              hipStream_t stream) {
    const float* h   = (const float*)d_in[0];
    const float* adj = (const float*)d_in[1];
    const float* W   = (const float*)d_in[2];
    const float* a   = (const float*)d_in[3];
    float* out = (float*)d_out;

    char* base = (char*)d_ws;
    float* Wh = (float*)base;                        base += (size_t)N * FOUT * 4;
    __hip_bfloat16* WhB = (__hip_bfloat16*)base;     base += (size_t)N * FOUT * 2;
    float* s2 = (float*)base;                        base += (size_t)N * 4;
    float* t2 = (float*)base;                        base += (size_t)N * 4 + 1024;
    float* acc_ws = (float*)base;                    base += (size_t)N * FOUT * 4;
    float* l_ws = (float*)base;                      base += (size_t)N * 4;
    unsigned* keys = (unsigned*)base;

    hipMemsetAsync(acc_ws, 0, ((size_t)N * FOUT + N) * 4 + 2 * sizeof(unsigned), stream);
    k_prep<<<N / 16, 256, 0, stream>>>(h, W, a, Wh, s2, t2, keys);
    k_pack<<<N / 32, 256, 0, stream>>>(Wh, WhB);
    dim3 ag(N / 16, JSPLIT);
    k_attn<<<ag, 256, 0, stream>>>(adj, WhB, s2, t2, keys, acc_ws, l_ws);
    k_final<<<N * FOUT / 4 / 256, 256, 0, stream>>>(acc_ws, l_ws, out);
}